// Round 21
// baseline (763.218 us; speedup 1.0000x reference)
//
#include <hip/hip_runtime.h>
#include <cstddef>
#include <cstdint>

#define N_     2048
#define H_     32
#define NEGF   (-1.0e30f)
#define LOG2E  1.4426950408889634f
#define C1F    (0.17677669529663687f * 1.4426950408889634f)   // (1/sqrt(32))*log2e
#define DEFER  16.0f
#define NCHUNK 8
#define CLEN   256            // N_/NCHUNK
#define NRTOT  8192           // B*N
#define PREC   20             // u32 per (chunk,row) pacc record: 16 bf16-pair + 4 f32

#define AS1 __attribute__((address_space(1)))
#define AS3 __attribute__((address_space(3)))

typedef unsigned short ushortT;
typedef short v8s __attribute__((ext_vector_type(8)));   // 8 bf16 = 4 VGPR (MFMA A/B frag)
typedef float v4f __attribute__((ext_vector_type(4)));   // MFMA C/D frag

struct AttnSmem {            // 24576 B
    ushortT k_lds[2][64 * 32];
    ushortT vt_lds[2][32 * 72];
    float4  x_lds[2][64];
    ushortT p_lds[4][16 * 40];
};
struct MergeSmem {           // 36352 B
    float wo_s[1024], w1_s[2048], w2_s[2048];
    float wq_s[1024], wk_s[1024], wv_s[1024];
    float ad_s[4][40], h1_s[4][36], h2_s[4][36], f_s[4][64];
    float pooled[4][32], a1[4][16];
};

__device__ __forceinline__ float exp2_fast(float x) {
    float r;
    asm("v_exp_f32 %0, %1" : "=v"(r) : "v"(x));
    return r;
}

// RNE float -> bf16 (u16 in low bits)
__device__ __forceinline__ unsigned f2bf(float x) {
    unsigned u = __builtin_bit_cast(unsigned, x);
    return (u + 0x7FFFu + ((u >> 16) & 1u)) >> 16;
}

// ---------------------------------------------------------------- fused adj->bitmask + h-init/qkv + counter zero
__global__ __launch_bounds__(256) void k_adjinit(const int* __restrict__ adj,
                                                 unsigned long long* __restrict__ mask,
                                                 const float* __restrict__ feats,
                                                 const float* __restrict__ W_in,
                                                 const float* __restrict__ Wq,
                                                 const float* __restrict__ Wk,
                                                 const float* __restrict__ Wv,
                                                 float* __restrict__ h,
                                                 ushortT* __restrict__ qb,
                                                 ushortT* __restrict__ kb,
                                                 ushortT* __restrict__ vb,
                                                 float* __restrict__ pool_ws,
                                                 unsigned* __restrict__ cnts) {
    __shared__ float hs[8][33];
    const int t = threadIdx.x;
    const int w = t >> 6, lane = t & 63;
    {
        const int wid = blockIdx.x * 4 + w;            // 8192 blocks * 4 waves
        const int* ap = adj + (size_t)wid * 512 + lane;
        int a[8];
#pragma unroll
        for (int k2 = 0; k2 < 8; ++k2) a[k2] = ap[k2 * 64];   // 8 loads in flight
#pragma unroll
        for (int k2 = 0; k2 < 8; ++k2) {
            unsigned long long mm = __ballot(a[k2] != 0);
            if (lane == 0) mask[wid * 8 + k2] = mm;
        }
    }

    if (blockIdx.x < 1024) {                       // h-init + layer-0 qkv
        int rl = t >> 5, c = t & 31;
        int row = blockIdx.x * 8 + rl;
        float f0 = feats[row * 3 + 0], f1 = feats[row * 3 + 1], f2 = feats[row * 3 + 2];
        float hv = f0 * W_in[c] + f1 * W_in[32 + c] + f2 * W_in[64 + c];
        hs[rl][c] = hv;
        h[(row << 5) + c] = hv;
        __syncthreads();
        float aq = 0.f, ak = 0.f, av = 0.f;
#pragma unroll
        for (int d = 0; d < 32; ++d) {
            float hd = hs[rl][d];
            aq += hd * Wq[(d << 5) + c];
            ak += hd * Wk[(d << 5) + c];
            av += hd * Wv[(d << 5) + c];
        }
        qb[(row << 5) + c] = (ushortT)f2bf(aq * C1F);   // q pre-scaled (log2 domain)
        kb[(row << 5) + c] = (ushortT)f2bf(ak);
        vb[(row << 5) + c] = (ushortT)f2bf(av);
    } else if (blockIdx.x == 1024) {
        if (t < 128) pool_ws[t] = 0.f;             // pooled-sum buffer (atomics target)
        for (int i = t; i < 3 * 129; i += 256) cnts[i] = 0;   // per-layer counters
    }
}

// ---------------------------------------------------------------- attention + fused merge tail (+ head)
// 1024 blocks = 128 rowblocks x 8 chunks. Each block: MFMA flash-attention on
// its (rowblock, 256-j chunk); writes per-chunk partials; last-finishing chunk
// block of each rowblock (decoupled atomic counter) merges the 64 rows,
// applies Wo/FF/x-update, emits next-layer qkv into the PING-PONG buffers
// (never in-place: siblings still read current-layer k/v), and on the last
// layer accumulates the pool; the final merger runs the output head.
__global__ __launch_bounds__(256) void k_attn(const ushortT* __restrict__ qb,
                                              const ushortT* __restrict__ kb,
                                              const ushortT* __restrict__ vb,
                                              ushortT* __restrict__ qout,
                                              ushortT* __restrict__ kout,
                                              ushortT* __restrict__ vout,
                                              const float* __restrict__ xin,
                                              float* __restrict__ xout,
                                              const unsigned long long* __restrict__ maskg,
                                              float* __restrict__ pm,
                                              float* __restrict__ ps,
                                              unsigned* __restrict__ pacc,
                                              float* __restrict__ hg,
                                              const float* __restrict__ Wo,
                                              const float* __restrict__ W1,
                                              const float* __restrict__ W2,
                                              const float* __restrict__ csp,
                                              const float* __restrict__ Wqn,
                                              const float* __restrict__ Wkn,
                                              const float* __restrict__ Wvn,
                                              float* __restrict__ pool_ws,
                                              const float* __restrict__ Wf1,
                                              const float* __restrict__ bf1,
                                              const float* __restrict__ Wf2,
                                              const float* __restrict__ bf2,
                                              float* __restrict__ outp,
                                              unsigned* __restrict__ cnt_rb,
                                              unsigned* __restrict__ cnt_all) {
    __shared__ __attribute__((aligned(16))) unsigned char smem_[sizeof(MergeSmem)];
    __shared__ unsigned elect;
    AttnSmem* as = (AttnSmem*)smem_;

    const int t = threadIdx.x;
    const int w = t >> 6, l = t & 63;
    const int g = l >> 4, q = l & 15;
    const int rowblk = blockIdx.x >> 3;      // 128 row-blocks of 64 rows
    const int cid    = blockIdx.x & 7;       // 8 chunks of 256 j
    const int bN = (rowblk >> 5) << 11;      // 32 row-blocks per batch
    const int j0 = cid << 8;
    const int rq = rowblk * 64 + w * 16 + q; // this lane's q-row

#define STAGE_TILE(BUF, TILE)                                                                  \
    do {                                                                                       \
        const int jj0 = (TILE) << 6;                                                           \
        __builtin_amdgcn_global_load_lds(                                                      \
            (const AS1 void*)((const char*)(kb + (((size_t)(bN + j0 + jj0)) << 5)) + t * 16),  \
            (AS3 void*)((char*)&as->k_lds[BUF][0] + t * 16), 16, 0, 0);                        \
        const int j_ = t & 63, grp_ = t >> 6;                                                  \
        const uint4 vv = *(const uint4*)(vb + (((size_t)(bN + j0 + jj0 + j_)) << 5) + grp_ * 8);\
        unsigned arr[4] = {vv.x, vv.y, vv.z, vv.w};                                            \
        _Pragma("unroll")                                                                      \
        for (int ii = 0; ii < 4; ++ii) {                                                       \
            as->vt_lds[BUF][(grp_ * 8 + 2 * ii) * 72 + j_]     = (ushortT)(arr[ii] & 0xffffu); \
            as->vt_lds[BUF][(grp_ * 8 + 2 * ii + 1) * 72 + j_] = (ushortT)(arr[ii] >> 16);     \
        }                                                                                      \
        if (t < 64) {                                                                          \
            const float* xp_ = xin + ((size_t)(bN + j0 + jj0 + t)) * 3;                        \
            float4 xv_; xv_.x = xp_[0]; xv_.y = xp_[1]; xv_.z = xp_[2]; xv_.w = 0.f;           \
            as->x_lds[BUF][t] = xv_;                                                           \
        }                                                                                      \
    } while (0)

    // ---- per-lane state
    const v8s qf = *(const v8s*)(qb + (((size_t)rq) << 5) + g * 8);  // Q B-frag (row q, d=8g..)
    const float xi0 = xin[rq * 3 + 0], xi1 = xin[rq * 3 + 1], xi2 = xin[rq * 3 + 2];

    v4f oA = {0.f, 0.f, 0.f, 0.f}, oB = {0.f, 0.f, 0.f, 0.f};
    float m = NEGF, sum = 0.f;
    float xa0 = 0.f, xa1 = 0.f, xa2 = 0.f;

    ushortT* pw = &as->p_lds[w][0];

    STAGE_TILE(0, 0);
    __syncthreads();

    int cur = 0;
#pragma unroll
    for (int tile = 0; tile < 4; ++tile) {
        if (tile < 3) STAGE_TILE(cur ^ 1, tile + 1);
        const unsigned long long mw = maskg[(((size_t)rq) << 5) + (cid << 2) + tile];

#pragma unroll
        for (int half = 0; half < 2; ++half) {
            const int jt = half * 32;
            v8s kA = *(const v8s*)(&as->k_lds[cur][0] + (jt + q) * 32 + g * 8);
            v8s kB = *(const v8s*)(&as->k_lds[cur][0] + (jt + 16 + q) * 32 + g * 8);
            v4f zero = {0.f, 0.f, 0.f, 0.f};
            v4f sA = __builtin_amdgcn_mfma_f32_16x16x32_bf16(kA, qf, zero, 0, 0, 0);
            v4f sB = __builtin_amdgcn_mfma_f32_16x16x32_bf16(kB, qf, zero, 0, 0, 0);

            float se[8];
            float4 xjA[4], xjB[4];
            float pot = NEGF;
#pragma unroll
            for (int reg = 0; reg < 4; ++reg) {
                const int jA = jt + 4 * g + reg, jB = jA + 16;
                xjA[reg] = as->x_lds[cur][jA];
                xjB[reg] = as->x_lds[cur][jB];
                float dA0 = xi0 - xjA[reg].x, dA1 = xi1 - xjA[reg].y, dA2 = xi2 - xjA[reg].z;
                float dB0 = xi0 - xjB[reg].x, dB1 = xi1 - xjB[reg].y, dB2 = xi2 - xjB[reg].z;
                float distA = fmaf(dA2, dA2, fmaf(dA1, dA1, dA0 * dA0));
                float distB = fmaf(dB2, dB2, fmaf(dB1, dB1, dB0 * dB0));
                const int bA = (int)((mw >> jA) & 1ULL);
                const int bB = (int)((mw >> jB) & 1ULL);
                se[reg]     = bA ? fmaf(distA, -LOG2E, sA[reg]) : NEGF;
                se[4 + reg] = bB ? fmaf(distB, -LOG2E, sB[reg]) : NEGF;
                pot = fmaxf(pot, fmaxf(se[reg], se[4 + reg]));
            }
            pot = fmaxf(pot, __shfl_xor(pot, 16));
            pot = fmaxf(pot, __shfl_xor(pot, 32));
            if (__any(pot - m > DEFER)) {
                float n2 = fmaxf(m, pot);
                float al = exp2_fast(m - n2);
                m = n2; sum *= al;
                v4f alv = {al, al, al, al};
                oA *= alv; oB *= alv;
                xa0 *= al; xa1 *= al; xa2 *= al;
            }
            float p[8];
#pragma unroll
            for (int i = 0; i < 8; ++i) { p[i] = exp2_fast(se[i] - m); sum += p[i]; }
#pragma unroll
            for (int reg = 0; reg < 4; ++reg) {
                xa0 = fmaf(p[reg], xjA[reg].x, fmaf(p[4 + reg], xjB[reg].x, xa0));
                xa1 = fmaf(p[reg], xjA[reg].y, fmaf(p[4 + reg], xjB[reg].y, xa1));
                xa2 = fmaf(p[reg], xjA[reg].z, fmaf(p[4 + reg], xjB[reg].z, xa2));
            }
            uint2 wA, wB;
            wA.x = f2bf(p[0]) | (f2bf(p[1]) << 16);
            wA.y = f2bf(p[2]) | (f2bf(p[3]) << 16);
            wB.x = f2bf(p[4]) | (f2bf(p[5]) << 16);
            wB.y = f2bf(p[6]) | (f2bf(p[7]) << 16);
            *(uint2*)(pw + q * 40 + 4 * g)      = wA;
            *(uint2*)(pw + q * 40 + 16 + 4 * g) = wB;
            v8s pf = *(const v8s*)(pw + q * 40 + 8 * g);
            v8s vA = *(const v8s*)(&as->vt_lds[cur][0] + q * 72 + jt + 8 * g);
            v8s vB = *(const v8s*)(&as->vt_lds[cur][0] + (16 + q) * 72 + jt + 8 * g);
            oA = __builtin_amdgcn_mfma_f32_16x16x32_bf16(vA, pf, oA, 0, 0, 0);
            oB = __builtin_amdgcn_mfma_f32_16x16x32_bf16(vB, pf, oB, 0, 0, 0);
        }
        __syncthreads();
        cur ^= 1;
    }
#undef STAGE_TILE

    sum += __shfl_xor(sum, 16); sum += __shfl_xor(sum, 32);
    xa0 += __shfl_xor(xa0, 16); xa0 += __shfl_xor(xa0, 32);
    xa1 += __shfl_xor(xa1, 16); xa1 += __shfl_xor(xa1, 32);
    xa2 += __shfl_xor(xa2, 16); xa2 += __shfl_xor(xa2, 32);

    unsigned* pb = pacc + ((size_t)cid * NRTOT + rq) * PREC;
    uint2 rA, rB;
    rA.x = f2bf(oA[0]) | (f2bf(oA[1]) << 16);
    rA.y = f2bf(oA[2]) | (f2bf(oA[3]) << 16);
    rB.x = f2bf(oB[0]) | (f2bf(oB[1]) << 16);
    rB.y = f2bf(oB[2]) | (f2bf(oB[3]) << 16);
    *(uint2*)(pb + 2 * g)     = rA;
    *(uint2*)(pb + 8 + 2 * g) = rB;
    if (g == 0) {
        float4 tl; tl.x = xa0; tl.y = xa1; tl.z = xa2; tl.w = 0.f;
        *(float4*)(pb + 16) = tl;
        pm[(((size_t)rq) << 3) + cid] = m;
        ps[(((size_t)rq) << 3) + cid] = sum;
    }

    // ---- decoupled merge election: last chunk block of this rowblock merges
    __threadfence();                       // release this block's partials
    __syncthreads();
    if (t == 0) elect = atomicAdd(&cnt_rb[rowblk], 1u);
    __syncthreads();
    if (elect != NCHUNK - 1) return;
    __threadfence();                       // acquire siblings' partials

    // ---- merge phase (LDS overlay; attn buffers dead)
    MergeSmem* ms = (MergeSmem*)smem_;
    const int lane = l;
    for (int i = t; i < 1024; i += 256) ms->wo_s[i] = Wo[i];
    for (int i = t; i < 2048; i += 256) { ms->w1_s[i] = W1[i]; ms->w2_s[i] = W2[i]; }
    if (Wqn) {
        for (int i = t; i < 1024; i += 256) {
            ms->wq_s[i] = Wqn[i]; ms->wk_s[i] = Wkn[i]; ms->wv_s[i] = Wvn[i];
        }
    }
    __syncthreads();

    float psum = 0.f;
#pragma unroll 1
    for (int ri = 0; ri < 16; ++ri) {
        const int r = rowblk * 64 + (w << 4) + ri;

        float pmv = NEGF, psv = 0.f;
        if (lane < NCHUNK) { pmv = pm[((size_t)r << 3) + lane]; psv = ps[((size_t)r << 3) + lane]; }
        float m_g = pmv;
#pragma unroll
        for (int off = 1; off < 64; off <<= 1) m_g = fmaxf(m_g, __shfl_xor(m_g, off));
        float scv = (lane < NCHUNK) ? exp2_fast(pmv - m_g) : 0.f;
        float sg = scv * psv;
#pragma unroll
        for (int off = 1; off < 64; off <<= 1) sg += __shfl_xor(sg, off);
        const float rinv = 1.0f / sg;

        const int off32 = (lane < 32) ? (lane >> 1) : (16 + ((lane - 32) & 3));
        const bool isTail = lane >= 32;
        const bool hiHalf = lane & 1;
        float ad = 0.f;
#pragma unroll
        for (int c = 0; c < NCHUNK; ++c) {
            float scc = __shfl(scv, c);
            unsigned u = pacc[((size_t)c * NRTOT + r) * PREC + off32];
            float f = isTail ? __builtin_bit_cast(float, u)
                             : __builtin_bit_cast(float, hiHalf ? (u & 0xffff0000u) : (u << 16));
            ad = fmaf(scc, f, ad);
        }
        if (lane < 35) ms->ad_s[w][lane] = ad;

        const int col = lane & 31;
        float hv = 0.f;
#pragma unroll
        for (int d = 0; d < 32; ++d) hv = fmaf(ms->ad_s[w][d], ms->wo_s[(d << 5) + col], hv);
        float h1 = 0.f;
        if (lane < 32) { h1 = hg[(((size_t)r) << 5) + lane] + hv * rinv; ms->h1_s[w][lane] = h1; }

        float f = 0.f;
#pragma unroll
        for (int d = 0; d < 32; ++d) f = fmaf(ms->h1_s[w][d], ms->w1_s[(d << 6) + lane], f);
        f = fmaxf(f, 0.f);
        ms->f_s[w][lane] = f;

        if (lane < 32) {
            float v2a = 0.f;
#pragma unroll
            for (int u = 0; u < 64; ++u) v2a = fmaf(ms->f_s[w][u], ms->w2_s[(u << 5) + lane], v2a);
            float hnew = h1 + v2a;
            hg[(((size_t)r) << 5) + lane] = hnew;
            ms->h2_s[w][lane] = hnew;
            psum += hnew;
        }

        if (lane < 3) {
            float o  = ms->ad_s[w][32 + lane] * rinv;
            float xi = xin[r * 3 + lane];
            xout[r * 3 + lane] = xi + csp[0] * (xi - o);
        }

        if (Wqn && lane < 32) {
            float aq = 0.f, ak = 0.f, av = 0.f;
#pragma unroll
            for (int d = 0; d < 32; ++d) {
                float hd = ms->h2_s[w][d];
                aq = fmaf(hd, ms->wq_s[(d << 5) + lane], aq);
                ak = fmaf(hd, ms->wk_s[(d << 5) + lane], ak);
                av = fmaf(hd, ms->wv_s[(d << 5) + lane], av);
            }
            qout[(((size_t)r) << 5) + lane] = (ushortT)f2bf(aq * C1F);
            kout[(((size_t)r) << 5) + lane] = (ushortT)f2bf(ak);
            vout[(((size_t)r) << 5) + lane] = (ushortT)f2bf(av);
        }
    }

    if (!pool_ws) return;

    // ---- last layer: pool accumulation + head election
    __syncthreads();
    if (lane < 32) ms->f_s[w][lane] = psum;
    __syncthreads();
    if (w == 0 && lane < 32) {
        float s4 = ms->f_s[0][lane] + ms->f_s[1][lane] + ms->f_s[2][lane] + ms->f_s[3][lane];
        atomicAdd(&pool_ws[((rowblk >> 5) << 5) + lane], s4);
    }
    __threadfence();
    __syncthreads();
    if (t == 0) elect = atomicAdd(cnt_all, 1u);
    __syncthreads();
    if (elect != 127) return;
    __threadfence();

    // ---- head (one block)
    if (t < 128) {
        int b = t >> 5, c = t & 31;
        ms->pooled[b][c] = pool_ws[t] * (1.0f / N_);
    }
    __syncthreads();
    if (t < 64) {
        int b = t >> 4, u = t & 15;
        float a = bf1[u];
#pragma unroll
        for (int d = 0; d < 32; ++d) a += ms->pooled[b][d] * Wf1[(d << 4) + u];
        ms->a1[b][u] = fmaxf(a, 0.f);
    }
    __syncthreads();
    if (t < 12) {
        int b = t / 3, o = t - b * 3;
        float v = bf2[o];
#pragma unroll
        for (int e = 0; e < 16; ++e) v += ms->a1[b][e] * Wf2[e * 3 + o];
        outp[b * 3 + o] = v;
    }
}

// ---------------------------------------------------------------- launch
extern "C" void kernel_launch(void* const* d_in, const int* in_sizes, int n_in,
                              void* d_out, int out_size, void* d_ws, size_t ws_size,
                              hipStream_t stream) {
    const float* feats = (const float*)d_in[0];
    const float* coors = (const float*)d_in[1];
    const int*   adj   = (const int*)d_in[2];
    const float* W_in  = (const float*)d_in[3];
    const float* Wq    = (const float*)d_in[4];
    const float* Wk    = (const float*)d_in[5];
    const float* Wv    = (const float*)d_in[6];
    const float* Wo    = (const float*)d_in[7];
    const float* W1    = (const float*)d_in[8];
    const float* W2    = (const float*)d_in[9];
    const float* csc   = (const float*)d_in[10];
    const float* Wf1   = (const float*)d_in[11];
    const float* bf1   = (const float*)d_in[12];
    const float* Wf2   = (const float*)d_in[13];
    const float* bf2   = (const float*)d_in[14];

    const size_t BNH = (size_t)4 * N_ * H_;   // 262144
    float* ws = (float*)d_ws;
    float* h  = ws;
    ushortT* qkv0 = (ushortT*)(ws + BNH);     // ping-pong qkv buffers (bf16)
    ushortT* qb0 = qkv0, *kb0 = qb0 + BNH, *vb0 = kb0 + BNH;
    ushortT* qb1 = vb0 + BNH, *kb1 = qb1 + BNH, *vb1 = kb1 + BNH;
    float* x0 = (float*)(vb1 + BNH);          // 24576 floats
    float* x1 = x0 + (size_t)4 * N_ * 3;
    unsigned long long* mask = (unsigned long long*)(x1 + (size_t)4 * N_ * 3);  // 262144 u64
    float* pm   = (float*)(mask + 262144);    // 8*8192 floats
    float* ps   = pm + (size_t)NCHUNK * NRTOT;
    unsigned* pacc = (unsigned*)(ps + (size_t)NCHUNK * NRTOT);  // 8*8192*20 u32 (5.2MB)
    float* pool_ws = (float*)(pacc + (size_t)NCHUNK * NRTOT * PREC);  // 128 floats
    unsigned* cnts = (unsigned*)(pool_ws + 128);                      // 3*129 u32

    k_adjinit<<<8192, 256, 0, stream>>>(adj, mask, feats, W_in, Wq, Wk, Wv,
                                        h, qb0, kb0, vb0, pool_ws, cnts);

    const float* xin[3]  = {coors, x0, x1};
    float*       xout[3] = {x0, x1, x0};
    ushortT* qbuf[2] = {qb0, qb1};
    ushortT* kbuf[2] = {kb0, kb1};
    ushortT* vbuf[2] = {vb0, vb1};
    for (int l = 0; l < 3; ++l) {
        const bool last = (l == 2);
        k_attn<<<1024, 256, 0, stream>>>(qbuf[l & 1], kbuf[l & 1], vbuf[l & 1],
                                         qbuf[(l + 1) & 1], kbuf[(l + 1) & 1], vbuf[(l + 1) & 1],
                                         xin[l], xout[l], mask, pm, ps, pacc, h,
                                         Wo + l * 1024, W1 + l * 2048, W2 + l * 2048,
                                         csc + l,
                                         last ? nullptr : Wq + (l + 1) * 1024,
                                         last ? nullptr : Wk + (l + 1) * 1024,
                                         last ? nullptr : Wv + (l + 1) * 1024,
                                         last ? pool_ws : nullptr,
                                         Wf1, bf1, Wf2, bf2, (float*)d_out,
                                         cnts + l * 129, cnts + l * 129 + 128);
    }
}

// Round 22
// 136.741 us; speedup vs baseline: 5.5815x; 5.5815x over previous
//
#include <hip/hip_runtime.h>
#include <cstddef>
#include <cstdint>

#define N_     2048
#define H_     32
#define NEGF   (-1.0e30f)
#define LOG2E  1.4426950408889634f
#define C1F    (0.17677669529663687f * 1.4426950408889634f)   // (1/sqrt(32))*log2e
#define DEFER  16.0f
#define NCHUNK 8
#define CLEN   256            // N_/NCHUNK
#define NRTOT  8192           // B*N
#define PREC   20             // u32 per (chunk,row) pacc record: 16 bf16-pair + 4 f32

#define AS1 __attribute__((address_space(1)))
#define AS3 __attribute__((address_space(3)))

typedef unsigned short ushortT;
typedef short v8s __attribute__((ext_vector_type(8)));   // 8 bf16 = 4 VGPR (MFMA A/B frag)
typedef float v4f __attribute__((ext_vector_type(4)));   // MFMA C/D frag

__device__ __forceinline__ float exp2_fast(float x) {
    float r;
    asm("v_exp_f32 %0, %1" : "=v"(r) : "v"(x));
    return r;
}

// RNE float -> bf16 (u16 in low bits)
__device__ __forceinline__ unsigned f2bf(float x) {
    unsigned u = __builtin_bit_cast(unsigned, x);
    return (u + 0x7FFFu + ((u >> 16) & 1u)) >> 16;
}

// ---------------------------------------------------------------- fused adj->bitmask + h-init/qkv + pool zero
// adj part: each wave handles 512 entries via 8 independent strided loads
// (32B/lane in flight -> latency hidden by ILP).
__global__ __launch_bounds__(256) void k_adjinit(const int* __restrict__ adj,
                                                 unsigned long long* __restrict__ mask,
                                                 const float* __restrict__ feats,
                                                 const float* __restrict__ W_in,
                                                 const float* __restrict__ Wq,
                                                 const float* __restrict__ Wk,
                                                 const float* __restrict__ Wv,
                                                 float* __restrict__ h,
                                                 ushortT* __restrict__ qb,
                                                 ushortT* __restrict__ kb,
                                                 ushortT* __restrict__ vb,
                                                 float* __restrict__ pool_ws) {
    __shared__ float hs[8][33];
    const int t = threadIdx.x;
    const int w = t >> 6, lane = t & 63;
    {
        const int wid = blockIdx.x * 4 + w;            // 8192 blocks * 4 waves
        const int* ap = adj + (size_t)wid * 512 + lane;
        int a[8];
#pragma unroll
        for (int k2 = 0; k2 < 8; ++k2) a[k2] = ap[k2 * 64];   // 8 loads in flight
#pragma unroll
        for (int k2 = 0; k2 < 8; ++k2) {
            unsigned long long mm = __ballot(a[k2] != 0);
            if (lane == 0) mask[wid * 8 + k2] = mm;
        }
    }

    if (blockIdx.x < 1024) {                       // h-init + layer-0 qkv
        int rl = t >> 5, c = t & 31;
        int row = blockIdx.x * 8 + rl;
        float f0 = feats[row * 3 + 0], f1 = feats[row * 3 + 1], f2 = feats[row * 3 + 2];
        float hv = f0 * W_in[c] + f1 * W_in[32 + c] + f2 * W_in[64 + c];
        hs[rl][c] = hv;
        h[(row << 5) + c] = hv;
        __syncthreads();
        float aq = 0.f, ak = 0.f, av = 0.f;
#pragma unroll
        for (int d = 0; d < 32; ++d) {
            float hd = hs[rl][d];
            aq += hd * Wq[(d << 5) + c];
            ak += hd * Wk[(d << 5) + c];
            av += hd * Wv[(d << 5) + c];
        }
        qb[(row << 5) + c] = (ushortT)f2bf(aq * C1F);   // q pre-scaled (log2 domain)
        kb[(row << 5) + c] = (ushortT)f2bf(ak);
        vb[(row << 5) + c] = (ushortT)f2bf(av);
    } else if (blockIdx.x == 1024 && t < 128) {
        pool_ws[t] = 0.f;                          // zero pooled-sum buffer (atomics target)
    }
}

// ---------------------------------------------------------------- attention core (MFMA, 256-j chunk)
// 4 waves x 16 q-rows; chunk = 4 x 64-j subtiles, K/V^T/x double-buffered.
__global__ __launch_bounds__(256) void k_attn(const ushortT* __restrict__ qb,
                                              const ushortT* __restrict__ kb,
                                              const ushortT* __restrict__ vb,
                                              const float* __restrict__ xin,
                                              const unsigned long long* __restrict__ maskg,
                                              float* __restrict__ pm,
                                              float* __restrict__ ps,
                                              unsigned* __restrict__ pacc) {
    __shared__ __attribute__((aligned(16))) ushortT k_lds[2][64 * 32];    // 2x4KB
    __shared__ __attribute__((aligned(16))) ushortT vt_lds[2][32 * 72];   // 2x4.5KB
    __shared__ __attribute__((aligned(16))) float4  x_lds[2][64];         // 2x1KB
    __shared__ __attribute__((aligned(16))) ushortT p_lds[4][16 * 40];    // per-wave P^T, 5KB

    const int t = threadIdx.x;
    const int w = t >> 6, l = t & 63;
    const int g = l >> 4, q = l & 15;
    const int rowblk = blockIdx.x >> 3;      // 128 row-blocks of 64 rows
    const int cid    = blockIdx.x & 7;       // 8 chunks of 256 j
    const int bN = (rowblk >> 5) << 11;      // 32 row-blocks per batch
    const int j0 = cid << 8;
    const int rq = rowblk * 64 + w * 16 + q; // this lane's q-row

#define STAGE_TILE(BUF, TILE)                                                                  \
    do {                                                                                       \
        const int jj0 = (TILE) << 6;                                                           \
        __builtin_amdgcn_global_load_lds(                                                      \
            (const AS1 void*)((const char*)(kb + (((size_t)(bN + j0 + jj0)) << 5)) + t * 16),  \
            (AS3 void*)((char*)&k_lds[BUF][0] + t * 16), 16, 0, 0);                            \
        const int j_ = t & 63, grp_ = t >> 6;                                                  \
        const uint4 vv = *(const uint4*)(vb + (((size_t)(bN + j0 + jj0 + j_)) << 5) + grp_ * 8);\
        unsigned arr[4] = {vv.x, vv.y, vv.z, vv.w};                                            \
        _Pragma("unroll")                                                                      \
        for (int ii = 0; ii < 4; ++ii) {                                                       \
            vt_lds[BUF][(grp_ * 8 + 2 * ii) * 72 + j_]     = (ushortT)(arr[ii] & 0xffffu);     \
            vt_lds[BUF][(grp_ * 8 + 2 * ii + 1) * 72 + j_] = (ushortT)(arr[ii] >> 16);         \
        }                                                                                      \
        if (t < 64) {                                                                          \
            const float* xp_ = xin + ((size_t)(bN + j0 + jj0 + t)) * 3;                        \
            float4 xv_; xv_.x = xp_[0]; xv_.y = xp_[1]; xv_.z = xp_[2]; xv_.w = 0.f;           \
            x_lds[BUF][t] = xv_;                                                               \
        }                                                                                      \
    } while (0)

    // ---- per-lane state
    const v8s qf = *(const v8s*)(qb + (((size_t)rq) << 5) + g * 8);  // Q B-frag (row q, d=8g..)
    const float xi0 = xin[rq * 3 + 0], xi1 = xin[rq * 3 + 1], xi2 = xin[rq * 3 + 2];

    v4f oA = {0.f, 0.f, 0.f, 0.f}, oB = {0.f, 0.f, 0.f, 0.f};
    float m = NEGF, sum = 0.f;
    float xa0 = 0.f, xa1 = 0.f, xa2 = 0.f;

    ushortT* pw = &p_lds[w][0];

    STAGE_TILE(0, 0);
    __syncthreads();

    int cur = 0;
#pragma unroll
    for (int tile = 0; tile < 4; ++tile) {
        if (tile < 3) STAGE_TILE(cur ^ 1, tile + 1);
        const unsigned long long mw = maskg[(((size_t)rq) << 5) + (cid << 2) + tile];

#pragma unroll
        for (int half = 0; half < 2; ++half) {
            const int jt = half * 32;
            v8s kA = *(const v8s*)(&k_lds[cur][0] + (jt + q) * 32 + g * 8);
            v8s kB = *(const v8s*)(&k_lds[cur][0] + (jt + 16 + q) * 32 + g * 8);
            v4f zero = {0.f, 0.f, 0.f, 0.f};
            v4f sA = __builtin_amdgcn_mfma_f32_16x16x32_bf16(kA, qf, zero, 0, 0, 0);
            v4f sB = __builtin_amdgcn_mfma_f32_16x16x32_bf16(kB, qf, zero, 0, 0, 0);

            float se[8];
            float4 xjA[4], xjB[4];
            float pot = NEGF;
#pragma unroll
            for (int reg = 0; reg < 4; ++reg) {
                const int jA = jt + 4 * g + reg, jB = jA + 16;
                xjA[reg] = x_lds[cur][jA];
                xjB[reg] = x_lds[cur][jB];
                float dA0 = xi0 - xjA[reg].x, dA1 = xi1 - xjA[reg].y, dA2 = xi2 - xjA[reg].z;
                float dB0 = xi0 - xjB[reg].x, dB1 = xi1 - xjB[reg].y, dB2 = xi2 - xjB[reg].z;
                float distA = fmaf(dA2, dA2, fmaf(dA1, dA1, dA0 * dA0));
                float distB = fmaf(dB2, dB2, fmaf(dB1, dB1, dB0 * dB0));
                const int bA = (int)((mw >> jA) & 1ULL);
                const int bB = (int)((mw >> jB) & 1ULL);
                se[reg]     = bA ? fmaf(distA, -LOG2E, sA[reg]) : NEGF;
                se[4 + reg] = bB ? fmaf(distB, -LOG2E, sB[reg]) : NEGF;
                pot = fmaxf(pot, fmaxf(se[reg], se[4 + reg]));
            }
            pot = fmaxf(pot, __shfl_xor(pot, 16));
            pot = fmaxf(pot, __shfl_xor(pot, 32));
            if (__any(pot - m > DEFER)) {
                float n2 = fmaxf(m, pot);
                float al = exp2_fast(m - n2);
                m = n2; sum *= al;
                v4f alv = {al, al, al, al};
                oA *= alv; oB *= alv;
                xa0 *= al; xa1 *= al; xa2 *= al;
            }
            float p[8];
#pragma unroll
            for (int i = 0; i < 8; ++i) { p[i] = exp2_fast(se[i] - m); sum += p[i]; }
#pragma unroll
            for (int reg = 0; reg < 4; ++reg) {
                xa0 = fmaf(p[reg], xjA[reg].x, fmaf(p[4 + reg], xjB[reg].x, xa0));
                xa1 = fmaf(p[reg], xjA[reg].y, fmaf(p[4 + reg], xjB[reg].y, xa1));
                xa2 = fmaf(p[reg], xjA[reg].z, fmaf(p[4 + reg], xjB[reg].z, xa2));
            }
            uint2 wA, wB;
            wA.x = f2bf(p[0]) | (f2bf(p[1]) << 16);
            wA.y = f2bf(p[2]) | (f2bf(p[3]) << 16);
            wB.x = f2bf(p[4]) | (f2bf(p[5]) << 16);
            wB.y = f2bf(p[6]) | (f2bf(p[7]) << 16);
            *(uint2*)(pw + q * 40 + 4 * g)      = wA;
            *(uint2*)(pw + q * 40 + 16 + 4 * g) = wB;
            v8s pf = *(const v8s*)(pw + q * 40 + 8 * g);
            v8s vA = *(const v8s*)(&vt_lds[cur][0] + q * 72 + jt + 8 * g);
            v8s vB = *(const v8s*)(&vt_lds[cur][0] + (16 + q) * 72 + jt + 8 * g);
            oA = __builtin_amdgcn_mfma_f32_16x16x32_bf16(vA, pf, oA, 0, 0, 0);
            oB = __builtin_amdgcn_mfma_f32_16x16x32_bf16(vB, pf, oB, 0, 0, 0);
        }
        __syncthreads();
        cur ^= 1;
    }
#undef STAGE_TILE

    sum += __shfl_xor(sum, 16); sum += __shfl_xor(sum, 32);
    xa0 += __shfl_xor(xa0, 16); xa0 += __shfl_xor(xa0, 32);
    xa1 += __shfl_xor(xa1, 16); xa1 += __shfl_xor(xa1, 32);
    xa2 += __shfl_xor(xa2, 16); xa2 += __shfl_xor(xa2, 32);

    unsigned* pb = pacc + ((size_t)cid * NRTOT + rq) * PREC;
    uint2 rA, rB;
    rA.x = f2bf(oA[0]) | (f2bf(oA[1]) << 16);
    rA.y = f2bf(oA[2]) | (f2bf(oA[3]) << 16);
    rB.x = f2bf(oB[0]) | (f2bf(oB[1]) << 16);
    rB.y = f2bf(oB[2]) | (f2bf(oB[3]) << 16);
    *(uint2*)(pb + 2 * g)     = rA;
    *(uint2*)(pb + 8 + 2 * g) = rB;
    if (g == 0) {
        float4 tl; tl.x = xa0; tl.y = xa1; tl.z = xa2; tl.w = 0.f;
        *(float4*)(pb + 16) = tl;
        pm[(((size_t)rq) << 3) + cid] = m;
        ps[(((size_t)rq) << 3) + cid] = sum;
    }
}

// ---------------------------------------------------------------- merge + epilogue + next-layer qkv (+pool)
__global__ __launch_bounds__(256) void k_mergefin(const float* __restrict__ pm,
                                                  const float* __restrict__ ps,
                                                  const unsigned* __restrict__ pacc,
                                                  float* __restrict__ hg,
                                                  const float* __restrict__ xin,
                                                  float* __restrict__ xout,
                                                  const float* __restrict__ Wo,
                                                  const float* __restrict__ W1,
                                                  const float* __restrict__ W2,
                                                  const float* __restrict__ csp,
                                                  const float* __restrict__ Wqn,
                                                  const float* __restrict__ Wkn,
                                                  const float* __restrict__ Wvn,
                                                  ushortT* __restrict__ qout,
                                                  ushortT* __restrict__ kout,
                                                  ushortT* __restrict__ vout,
                                                  float* __restrict__ pool_ws) {
    __shared__ float wo_s[1024];
    __shared__ float w1_s[2048];
    __shared__ float w2_s[2048];
    __shared__ float wq_s[1024];
    __shared__ float wk_s[1024];
    __shared__ float wv_s[1024];
    __shared__ float ad_s[4][40];
    __shared__ float h1_s[4][36];
    __shared__ float h2_s[4][36];
    __shared__ float f_s[4][64];

    const int t = threadIdx.x, w = t >> 6, lane = t & 63;
    for (int i = t; i < 1024; i += 256) wo_s[i] = Wo[i];
    for (int i = t; i < 2048; i += 256) { w1_s[i] = W1[i]; w2_s[i] = W2[i]; }
    if (Wqn) {
        for (int i = t; i < 1024; i += 256) {
            wq_s[i] = Wqn[i]; wk_s[i] = Wkn[i]; wv_s[i] = Wvn[i];
        }
    }
    __syncthreads();

    float psum = 0.f;                  // pooled hnew accumulator (lane<32 meaningful)

#pragma unroll 1
    for (int ri = 0; ri < 4; ++ri) {
        const int r = (blockIdx.x << 4) + (w << 2) + ri;

        // merge stats across 8 chunks
        float pmv = NEGF, psv = 0.f;
        if (lane < NCHUNK) { pmv = pm[((size_t)r << 3) + lane]; psv = ps[((size_t)r << 3) + lane]; }
        float m_g = pmv;
#pragma unroll
        for (int off = 1; off < 64; off <<= 1) m_g = fmaxf(m_g, __shfl_xor(m_g, off));
        float scv = (lane < NCHUNK) ? exp2_fast(pmv - m_g) : 0.f;
        float sg = scv * psv;
#pragma unroll
        for (int off = 1; off < 64; off <<= 1) sg += __shfl_xor(sg, off);
        const float rinv = 1.0f / sg;

        // merged accumulator, lane = d
        const int off32 = (lane < 32) ? (lane >> 1) : (16 + ((lane - 32) & 3));
        const bool isTail = lane >= 32;
        const bool hiHalf = lane & 1;
        float ad = 0.f;
#pragma unroll
        for (int c = 0; c < NCHUNK; ++c) {
            float scc = __shfl(scv, c);
            unsigned u = pacc[((size_t)c * NRTOT + r) * PREC + off32];
            float f = isTail ? __builtin_bit_cast(float, u)
                             : __builtin_bit_cast(float, hiHalf ? (u & 0xffff0000u) : (u << 16));
            ad = fmaf(scc, f, ad);
        }
        if (lane < 35) ad_s[w][lane] = ad;

        // Wo matmul
        const int col = lane & 31;
        float hv = 0.f;
#pragma unroll
        for (int d = 0; d < 32; ++d) hv = fmaf(ad_s[w][d], wo_s[(d << 5) + col], hv);
        float h1 = 0.f;
        if (lane < 32) { h1 = hg[(((size_t)r) << 5) + lane] + hv * rinv; h1_s[w][lane] = h1; }

        // FF up
        float f = 0.f;
#pragma unroll
        for (int d = 0; d < 32; ++d) f = fmaf(h1_s[w][d], w1_s[(d << 6) + lane], f);
        f = fmaxf(f, 0.f);
        f_s[w][lane] = f;

        // FF down + residual
        if (lane < 32) {
            float v2a = 0.f;
#pragma unroll
            for (int u = 0; u < 64; ++u) v2a = fmaf(f_s[w][u], w2_s[(u << 5) + lane], v2a);
            float hnew = h1 + v2a;
            hg[(((size_t)r) << 5) + lane] = hnew;
            h2_s[w][lane] = hnew;
            psum += hnew;
        }

        // equivariant x update
        if (lane < 3) {
            float o  = ad_s[w][32 + lane] * rinv;
            float xi = xin[r * 3 + lane];
            xout[r * 3 + lane] = xi + csp[0] * (xi - o);
        }

        // fused next-layer qkv
        if (Wqn && lane < 32) {
            float aq = 0.f, ak = 0.f, av = 0.f;
#pragma unroll
            for (int d = 0; d < 32; ++d) {
                float hd = h2_s[w][d];
                aq = fmaf(hd, wq_s[(d << 5) + lane], aq);
                ak = fmaf(hd, wk_s[(d << 5) + lane], ak);
                av = fmaf(hd, wv_s[(d << 5) + lane], av);
            }
            qout[(((size_t)r) << 5) + lane] = (ushortT)f2bf(aq * C1F);
            kout[(((size_t)r) << 5) + lane] = (ushortT)f2bf(ak);
            vout[(((size_t)r) << 5) + lane] = (ushortT)f2bf(av);
        }
    }

    // last layer: pool accumulation (block covers 16 rows of one batch)
    if (pool_ws) {
        __syncthreads();
        if (lane < 32) f_s[w][lane] = psum;      // reuse f_s as reduce buffer
        __syncthreads();
        if (w == 0 && lane < 32) {
            float s4 = f_s[0][lane] + f_s[1][lane] + f_s[2][lane] + f_s[3][lane];
            const int batch = blockIdx.x >> 7;   // 128 blocks per batch
            atomicAdd(&pool_ws[(batch << 5) + lane], s4);
        }
    }
}

// ---------------------------------------------------------------- head (tiny)
__global__ __launch_bounds__(256) void k_head(const float* __restrict__ pool_ws,
                                              const float* __restrict__ Wf1,
                                              const float* __restrict__ bf1,
                                              const float* __restrict__ Wf2,
                                              const float* __restrict__ bf2,
                                              float* __restrict__ out) {
    __shared__ float pooled[4][32];
    __shared__ float a1[4][16];
    const int t = threadIdx.x;
    if (t < 128) {
        int b = t >> 5, c = t & 31;
        pooled[b][c] = pool_ws[t] * (1.0f / N_);
    }
    __syncthreads();
    if (t < 64) {
        int b = t >> 4, u = t & 15;
        float a = bf1[u];
#pragma unroll
        for (int d = 0; d < 32; ++d) a += pooled[b][d] * Wf1[(d << 4) + u];
        a1[b][u] = fmaxf(a, 0.f);
    }
    __syncthreads();
    if (t < 12) {
        int b = t / 3, o = t - b * 3;
        float v = bf2[o];
#pragma unroll
        for (int e = 0; e < 16; ++e) v += a1[b][e] * Wf2[e * 3 + o];
        out[b * 3 + o] = v;
    }
}

// ---------------------------------------------------------------- launch
extern "C" void kernel_launch(void* const* d_in, const int* in_sizes, int n_in,
                              void* d_out, int out_size, void* d_ws, size_t ws_size,
                              hipStream_t stream) {
    const float* feats = (const float*)d_in[0];
    const float* coors = (const float*)d_in[1];
    const int*   adj   = (const int*)d_in[2];
    const float* W_in  = (const float*)d_in[3];
    const float* Wq    = (const float*)d_in[4];
    const float* Wk    = (const float*)d_in[5];
    const float* Wv    = (const float*)d_in[6];
    const float* Wo    = (const float*)d_in[7];
    const float* W1    = (const float*)d_in[8];
    const float* W2    = (const float*)d_in[9];
    const float* csc   = (const float*)d_in[10];
    const float* Wf1   = (const float*)d_in[11];
    const float* bf1   = (const float*)d_in[12];
    const float* Wf2   = (const float*)d_in[13];
    const float* bf2   = (const float*)d_in[14];

    const size_t BNH = (size_t)4 * N_ * H_;   // 262144
    float* ws = (float*)d_ws;
    float* h  = ws;
    ushortT* qb = (ushortT*)(ws + BNH);       // BNH ushorts each (512KB)
    ushortT* kb = qb + BNH;
    ushortT* vb = kb + BNH;
    float* x0 = (float*)(vb + BNH);           // 24576 floats
    float* x1 = x0 + (size_t)4 * N_ * 3;
    unsigned long long* mask = (unsigned long long*)(x1 + (size_t)4 * N_ * 3);  // 262144 u64
    float* pm   = (float*)(mask + 262144);    // 8*8192 floats
    float* ps   = pm + (size_t)NCHUNK * NRTOT;
    unsigned* pacc = (unsigned*)(ps + (size_t)NCHUNK * NRTOT);  // 8*8192*20 u32 (5.2MB)
    float* pool_ws = (float*)(pacc + (size_t)NCHUNK * NRTOT * PREC);  // 128 floats

    k_adjinit<<<8192, 256, 0, stream>>>(adj, mask, feats, W_in, Wq, Wk, Wv,
                                        h, qb, kb, vb, pool_ws);

    const float* xin[3]  = {coors, x0, x1};
    float*       xout[3] = {x0, x1, x0};
    for (int l = 0; l < 3; ++l) {
        k_attn<<<1024, 256, 0, stream>>>(qb, kb, vb, xin[l], mask, pm, ps, pacc);
        const bool last = (l == 2);
        k_mergefin<<<512, 256, 0, stream>>>(pm, ps, pacc, h, xin[l], xout[l],
                                            Wo + l * 1024, W1 + l * 2048, W2 + l * 2048,
                                            csc + l,
                                            last ? nullptr : Wq + (l + 1) * 1024,
                                            last ? nullptr : Wk + (l + 1) * 1024,
                                            last ? nullptr : Wv + (l + 1) * 1024,
                                            qb, kb, vb,
                                            last ? pool_ws : nullptr);
    }
    k_head<<<1, 256, 0, stream>>>(pool_ws, Wf1, bf1, Wf2, bf2, (float*)d_out);
}